// Round 2
// baseline (236.142 us; speedup 1.0000x reference)
//
#include <hip/hip_runtime.h>
#include <hip/hip_bf16.h>

#define NEG_INF -9.0e15f

constexpr int B = 4, N = 2048, FIN = 128, H = 4, D = 32;
constexpr int BH = B * H;

// ---------------------------------------------------------------------------
// Kernel 1: Wh (bf16) = h @ W per head, plus e_src/e_dst (f32).
// 256 thr: t = fh*128 + hh*32 + d.  Each thread holds half a W column (64
// f32) in registers; h rows staged in LDS; fh halves combined through LDS.
// ---------------------------------------------------------------------------
constexpr int NPB = 16;  // h-rows per block

__global__ __launch_bounds__(256) void wh_kernel(
    const float* __restrict__ h, const float* __restrict__ W,
    const float* __restrict__ a, __hip_bfloat16* __restrict__ Whb,
    float* __restrict__ es, float* __restrict__ ed) {
  __shared__ float hsh[NPB][FIN];    // 8 KB
  __shared__ float part[NPB][H][D];  // 8 KB
  const int t = threadIdx.x;
  const int fh = t >> 7, hh = (t >> 5) & 3, d = t & 31;

  float Wr[64];
#pragma unroll
  for (int ff = 0; ff < 64; ++ff)
    Wr[ff] = W[hh * (FIN * D) + (fh * 64 + ff) * D + d];

  const int n0 = blockIdx.x * NPB;
  for (int idx = t; idx < NPB * FIN; idx += 256)
    hsh[idx >> 7][idx & 127] = h[(size_t)n0 * FIN + idx];
  __syncthreads();

  float accs[NPB];
#pragma unroll
  for (int r = 0; r < NPB; ++r) {
    float acc = 0.f;
    const float* hr = &hsh[r][fh * 64];
#pragma unroll
    for (int f4 = 0; f4 < 16; ++f4) {
      float4 hv = *(const float4*)(hr + f4 * 4);
      acc += hv.x * Wr[f4 * 4 + 0];
      acc += hv.y * Wr[f4 * 4 + 1];
      acc += hv.z * Wr[f4 * 4 + 2];
      acc += hv.w * Wr[f4 * 4 + 3];
    }
    accs[r] = acc;
  }
  if (fh == 0) {
#pragma unroll
    for (int r = 0; r < NPB; ++r) part[r][hh][d] = accs[r];
  }
  __syncthreads();
  if (fh == 1) {
    const int b = n0 / N;
    const int bh = b * H + hh;
    const float asrc = a[hh * 2 * D + d];
    const float adst = a[hh * 2 * D + D + d];
#pragma unroll
    for (int r = 0; r < NPB; ++r) {
      const int n = (n0 & (N - 1)) + r;
      const float wh = accs[r] + part[r][hh][d];
      Whb[((size_t)bh * N + n) * D + d] = __float2bfloat16(wh);
      float vs = wh * asrc, vd = wh * adst;
#pragma unroll
      for (int o = 16; o >= 1; o >>= 1) {
        vs += __shfl_xor(vs, o, 64);
        vd += __shfl_xor(vd, o, 64);
      }
      if (d == 0) {
        es[(size_t)bh * N + n] = vs;
        ed[(size_t)bh * N + n] = vd;
      }
    }
  }
}

// ---------------------------------------------------------------------------
// Kernel 2: pack adj (int32 0/1) into a bitmask, one u64 word per wave.
// ---------------------------------------------------------------------------
__global__ __launch_bounds__(256) void pack_kernel(
    const int* __restrict__ adj, unsigned long long* __restrict__ mask) {
  const int gid = blockIdx.x * 256 + threadIdx.x;
  const int wdx = gid >> 6;  // word index, N*N/64 total
  const int lane = threadIdx.x & 63;
  const int i = wdx >> 5;          // row (32 words per row)
  const int jb = (wdx & 31) << 6;  // col base
  const int v = adj[(size_t)i * N + jb + lane];
  const unsigned long long m = __ballot(v > 0);
  if (lane == 0) mask[wdx] = m;
}

// ---------------------------------------------------------------------------
// Kernel 3: fused masked softmax + PV.  Wave owns 2 rows; lanes = j.
// Pass 1: row max (cheap).  Pass 2: p in-lane, acc[2][32] in registers,
// bf16 Wh loads (4 x dwordx4).  Final reduce via one LDS round per row.
// ---------------------------------------------------------------------------
constexpr int RPW = 2;         // rows per wave
constexpr int NW = 4;          // waves per block
constexpr int RPB = RPW * NW;  // 8 rows per block
constexpr int NCH = N / 64;    // 32 j-chunks

__global__ __launch_bounds__(256) void attn_kernel(
    const float* __restrict__ es, const float* __restrict__ ed,
    const __hip_bfloat16* __restrict__ Whb,
    const unsigned long long* __restrict__ mask,
    float* __restrict__ out) {
  __shared__ float edsh[N];          // 8 KB
  __shared__ float red[NW][64][33];  // 33 KB, 33-stride = conflict-free
  __shared__ float invsh[NW][RPW];

  const int bh = blockIdx.x >> 8;  // N/RPB == 256 tiles per bh
  const int tile = blockIdx.x & 255;
  const int b = bh >> 2, hh = bh & 3;
  const int tid = threadIdx.x, lane = tid & 63, w = tid >> 6;

  for (int idx = tid; idx < N; idx += 256)
    edsh[idx] = ed[(size_t)bh * N + idx];
  __syncthreads();

  const int i0 = tile * RPB + w * RPW;
  const float es0 = es[(size_t)bh * N + i0];
  const float es1 = es[(size_t)bh * N + i0 + 1];
  const unsigned long long* m0 = mask + (size_t)i0 * NCH;
  const unsigned long long* m1 = mask + (size_t)(i0 + 1) * NCH;

  // ---- pass 1: row maxima ----
  float mx0 = NEG_INF, mx1 = NEG_INF;
  for (int jt = 0; jt < NCH; ++jt) {
    const float edv = edsh[jt * 64 + lane];
    const unsigned long long w0 = m0[jt], w1 = m1[jt];
    float e0 = es0 + edv; e0 = e0 > 0.f ? e0 : 0.2f * e0;
    float e1 = es1 + edv; e1 = e1 > 0.f ? e1 : 0.2f * e1;
    mx0 = fmaxf(mx0, ((w0 >> lane) & 1ull) ? e0 : NEG_INF);
    mx1 = fmaxf(mx1, ((w1 >> lane) & 1ull) ? e1 : NEG_INF);
  }
#pragma unroll
  for (int o = 32; o >= 1; o >>= 1) {
    mx0 = fmaxf(mx0, __shfl_xor(mx0, o, 64));
    mx1 = fmaxf(mx1, __shfl_xor(mx1, o, 64));
  }

  // ---- pass 2: exp + PV ----
  float sum0 = 0.f, sum1 = 0.f;
  float acc0[D] = {}, acc1[D] = {};
  const __hip_bfloat16* whbase = Whb + (size_t)bh * N * D;
  for (int jt = 0; jt < NCH; ++jt) {
    const int j = jt * 64 + lane;
    const float edv = edsh[j];
    const unsigned long long w0 = m0[jt], w1 = m1[jt];
    float e0 = es0 + edv; e0 = e0 > 0.f ? e0 : 0.2f * e0;
    float e1 = es1 + edv; e1 = e1 > 0.f ? e1 : 0.2f * e1;
    const float p0 = __expf((((w0 >> lane) & 1ull) ? e0 : NEG_INF) - mx0);
    const float p1 = __expf((((w1 >> lane) & 1ull) ? e1 : NEG_INF) - mx1);
    sum0 += p0;
    sum1 += p1;
    if (p0 > 0.f || p1 > 0.f) {
      const uint4* wp = (const uint4*)(whbase + (size_t)j * D);
      const uint4 q0 = wp[0], q1 = wp[1], q2 = wp[2], q3 = wp[3];
#define UNP2(u, db)                                        \
  {                                                        \
    const float f0 = __uint_as_float((u) << 16);           \
    const float f1 = __uint_as_float((u) & 0xffff0000u);   \
    acc0[db] += p0 * f0;                                   \
    acc1[db] += p1 * f0;                                   \
    acc0[(db) + 1] += p0 * f1;                             \
    acc1[(db) + 1] += p1 * f1;                             \
  }
#define UNP8(q, db) UNP2(q.x, db) UNP2(q.y, (db) + 2) UNP2(q.z, (db) + 4) UNP2(q.w, (db) + 6)
      UNP8(q0, 0) UNP8(q1, 8) UNP8(q2, 16) UNP8(q3, 24)
#undef UNP8
#undef UNP2
    }
  }
#pragma unroll
  for (int o = 32; o >= 1; o >>= 1) {
    sum0 += __shfl_xor(sum0, o, 64);
    sum1 += __shfl_xor(sum1, o, 64);
  }
  if (lane == 0) {
    invsh[w][0] = 1.f / sum0;
    invsh[w][1] = 1.f / sum1;
  }

  // ---- cross-lane reduction through LDS, one row at a time ----
#pragma unroll
  for (int r = 0; r < RPW; ++r) {
#pragma unroll
    for (int dd = 0; dd < D; ++dd)
      red[w][lane][dd] = (r == 0) ? acc0[dd] : acc1[dd];
    __syncthreads();
    if (tid < 128) {
      const int wq = tid >> 5, dd = tid & 31;
      float s = 0.f;
      for (int l = 0; l < 64; ++l) s += red[wq][l][dd];
      const int i = tile * RPB + wq * RPW + r;
      out[((size_t)b * N + i) * (H * D) + hh * D + dd] = s * invsh[wq][r];
    }
    __syncthreads();
  }
}

// ---------------------------------------------------------------------------
extern "C" void kernel_launch(void* const* d_in, const int* in_sizes, int n_in,
                              void* d_out, int out_size, void* d_ws,
                              size_t ws_size, hipStream_t stream) {
  const float* h = (const float*)d_in[0];
  const int* adj = (const int*)d_in[1];
  const float* W = (const float*)d_in[2];
  const float* a = (const float*)d_in[3];
  char* ws = (char*)d_ws;
  __hip_bfloat16* Whb = (__hip_bfloat16*)ws;  // 2 MB: BH*N*D bf16
  float* es = (float*)(ws + (2u << 20));                    // 128 KB
  float* ed = (float*)(ws + (2u << 20) + (128u << 10));     // 128 KB
  unsigned long long* mask =
      (unsigned long long*)(ws + (2u << 20) + (256u << 10));  // 512 KB
  float* out = (float*)d_out;

  wh_kernel<<<B * N / NPB, 256, 0, stream>>>(h, W, a, Whb, es, ed);
  pack_kernel<<<N * N / 256, 256, 0, stream>>>(adj, mask);
  attn_kernel<<<BH * (N / RPB), 256, 0, stream>>>(es, ed, Whb, mask, out);
}

// Round 5
// 145.252 us; speedup vs baseline: 1.6257x; 1.6257x over previous
//
#include <hip/hip_runtime.h>
#include <hip/hip_bf16.h>

typedef unsigned short u16;
using f32x4 = __attribute__((ext_vector_type(4))) float;
using short8 = __attribute__((ext_vector_type(8))) short;

constexpr int B_ = 4, N_ = 2048, FIN = 128, H_ = 4, D_ = 32;
constexpr int BH = B_ * H_;

// RNE f32 pair -> packed bf16x2 (lo in [15:0], hi in [31:16]); inputs finite.
static __device__ __forceinline__ unsigned int pk_bf16(float lo, float hi) {
  unsigned int ul = __float_as_uint(lo);
  unsigned int uh = __float_as_uint(hi);
  ul = (ul + 0x7fffu + ((ul >> 16) & 1u)) >> 16;
  uh = (uh + 0x7fffu + ((uh >> 16) & 1u)) & 0xffff0000u;
  return ul | uh;
}

// ---------------------------------------------------------------------------
// Kernel 1: WhT (bf16, [bh*D+d][n]) = (h @ W)^T per head, plus e_src/e_dst.
// ---------------------------------------------------------------------------
constexpr int NPB = 16;  // h-rows per block

__global__ __launch_bounds__(256) void wh_kernel(
    const float* __restrict__ h, const float* __restrict__ W,
    const float* __restrict__ a, u16* __restrict__ WhT,
    float* __restrict__ es, float* __restrict__ ed) {
  __shared__ float hsh[NPB][FIN];
  __shared__ float part[NPB][H_][D_];
  const int t = threadIdx.x;
  const int fh = t >> 7, hh = (t >> 5) & 3, d = t & 31;

  float Wr[64];
#pragma unroll
  for (int ff = 0; ff < 64; ++ff)
    Wr[ff] = W[hh * (FIN * D_) + (fh * 64 + ff) * D_ + d];

  const int n0 = blockIdx.x * NPB;
  for (int idx = t; idx < NPB * FIN; idx += 256)
    hsh[idx >> 7][idx & 127] = h[(size_t)n0 * FIN + idx];
  __syncthreads();

  float accs[NPB];
#pragma unroll
  for (int r = 0; r < NPB; ++r) {
    float acc = 0.f;
    const float* hr = &hsh[r][fh * 64];
#pragma unroll
    for (int f4 = 0; f4 < 16; ++f4) {
      float4 hv = *(const float4*)(hr + f4 * 4);
      acc += hv.x * Wr[f4 * 4 + 0];
      acc += hv.y * Wr[f4 * 4 + 1];
      acc += hv.z * Wr[f4 * 4 + 2];
      acc += hv.w * Wr[f4 * 4 + 3];
    }
    accs[r] = acc;
  }
  if (fh == 0) {
#pragma unroll
    for (int r = 0; r < NPB; ++r) part[r][hh][d] = accs[r];
  }
  __syncthreads();
  if (fh == 1) {
    const int b = n0 / N_;
    const int bh = b * H_ + hh;
    const int n0r = n0 & (N_ - 1);
    const float asrc = a[hh * 2 * D_ + d];
    const float adst = a[hh * 2 * D_ + D_ + d];
    union { u16 s[16]; uint4 q[2]; } wbuf;
#pragma unroll
    for (int r = 0; r < NPB; ++r) {
      const float wh = accs[r] + part[r][hh][d];
      union { __hip_bfloat16 h; u16 u; } cv;
      cv.h = __float2bfloat16(wh);
      wbuf.s[r] = cv.u;
      float vs = wh * asrc, vd = wh * adst;
#pragma unroll
      for (int o = 16; o >= 1; o >>= 1) {
        vs += __shfl_xor(vs, o, 64);
        vd += __shfl_xor(vd, o, 64);
      }
      if (d == 0) {
        es[(size_t)bh * N_ + n0r + r] = vs;
        ed[(size_t)bh * N_ + n0r + r] = vd;
      }
    }
    u16* dst = WhT + ((size_t)(bh * 32 + d)) * N_ + n0r;
    *(uint4*)dst = wbuf.q[0];
    *(uint4*)(dst + 8) = wbuf.q[1];
  }
}

// ---------------------------------------------------------------------------
// Kernel 2: pack adj into a bitmask (u64 word per 64 cols).
// ---------------------------------------------------------------------------
__global__ __launch_bounds__(256) void pack_kernel(
    const int* __restrict__ adj, unsigned long long* __restrict__ mask) {
  const int gid = blockIdx.x * 256 + threadIdx.x;
  const int wdx = gid >> 6;
  const int lane = threadIdx.x & 63;
  const int i = wdx >> 5;
  const int jb = (wdx & 31) << 6;
  const int v = adj[(size_t)i * N_ + jb + lane];
  const unsigned long long m = __ballot(v > 0);
  if (lane == 0) mask[wdx] = m;
}

// ---------------------------------------------------------------------------
// Kernel 2b: true masked per-row ed max: rowmaxed[bh][i] = max_{adj[i][j]} ed[j]
// (leaky is monotone, so leaky(es_i + rowmaxed) is the exact softmax shift).
// ---------------------------------------------------------------------------
constexpr int RMROWS = 32;

__global__ __launch_bounds__(256) void rowmax_kernel(
    const float* __restrict__ ed, const unsigned int* __restrict__ mask32,
    float* __restrict__ rowmaxed) {
  __shared__ float edL[N_];                 // 8 KB
  __shared__ unsigned int msh[RMROWS][65];  // 8.1 KB
  const int bh = blockIdx.x >> 6;  // 64 row-chunks per bh
  const int r0 = (blockIdx.x & 63) * RMROWS;
  const int tid = threadIdx.x, lane = tid & 63, w = tid >> 6;

  const float* edb = ed + (size_t)bh * N_;
#pragma unroll
  for (int q = 0; q < 8; ++q) edL[tid + q * 256] = edb[tid + q * 256];
  const unsigned int* mrow = mask32 + (size_t)r0 * 64;
#pragma unroll
  for (int q = 0; q < 8; ++q) {
    const int idx = tid + q * 256;
    msh[idx >> 6][idx & 63] = mrow[(idx >> 6) * 64 + (idx & 63)];
  }
  __syncthreads();

  for (int r = w; r < RMROWS; r += 4) {
    float mx = -3.0e38f;
#pragma unroll
    for (int q = 0; q < 32; ++q) {  // j = q*64 + lane
      const unsigned int mword = msh[r][q * 2 + (lane >> 5)];
      const float v = edL[q * 64 + lane];
      mx = ((mword >> (lane & 31)) & 1u) ? fmaxf(mx, v) : mx;
    }
#pragma unroll
    for (int o = 32; o >= 1; o >>= 1) mx = fmaxf(mx, __shfl_xor(mx, o, 64));
    if (lane == 0) rowmaxed[(size_t)bh * N_ + r0 + r] = mx;
  }
}

// ---------------------------------------------------------------------------
// Kernel 3: fused masked-softmax + MFMA PV (true row max -> no underflow).
// ---------------------------------------------------------------------------
constexpr int ROWS = 32;
constexpr int KSTEPS = 32;  // 1024 j per half / 32

__global__ __launch_bounds__(256) void attn_kernel(
    const float* __restrict__ es, const float* __restrict__ ed,
    const float* __restrict__ rowmaxed, const u16* __restrict__ WhT,
    const unsigned int* __restrict__ mask32, float* __restrict__ out) {
  __shared__ float edsh[N_];                   // 8 KB
  __shared__ unsigned char maskL[ROWS * 260];  // 8.1 KB
  __shared__ u16 whL[2][2][32 * 40];           // 10 KB
  __shared__ float redc[2][2][16][32];         // 16 KB
  __shared__ float sumsh[2][2][16];
  __shared__ float essh[ROWS];
  __shared__ float rmsh[ROWS];

  const int bh = blockIdx.x >> 6;
  const int it = blockIdx.x & 63;
  const int i0 = it * ROWS;
  const int tid = threadIdx.x, lane = tid & 63, w = tid >> 6;
  const int tile = w & 1, jh = w >> 1;

  // ---- prologue: stage ed, mask rows, es, rowmax, step-0 Wh tiles ----
  const float* edb = ed + (size_t)bh * N_;
  float4 e0 = *(const float4*)(edb + tid * 8);
  float4 e1 = *(const float4*)(edb + tid * 8 + 4);
  *(float4*)&edsh[tid * 8] = e0;
  *(float4*)&edsh[tid * 8 + 4] = e1;

  const unsigned int* mrow = mask32 + (size_t)i0 * 64;
#pragma unroll
  for (int q = 0; q < 8; ++q) {
    const int idx = tid + q * 256;
    const int r = idx >> 6, c = idx & 63;
    ((unsigned int*)maskL)[r * 65 + c] = mrow[r * 64 + c];
  }
  if (tid < ROWS) {
    essh[tid] = es[(size_t)bh * N_ + i0 + tid];
    rmsh[tid] = rowmaxed[(size_t)bh * N_ + i0 + tid];
  }

  const int jt = tid >> 7;         // j-half this thread stages
  const int sr = (tid >> 2) & 31;  // d-row
  const int sc = tid & 3;          // 16B chunk
  const u16* wsrc = WhT + ((size_t)(bh * 32 + sr)) * N_ + jt * 1024 + sc * 8;
  *(uint4*)&whL[0][jt][sr * 40 + sc * 8] = *(const uint4*)wsrc;
  __syncthreads();

  const int row16 = lane & 15, kg = lane >> 4;
  const int row32 = tile * 16 + row16;
  const float esr = essh[row32];
  const float xm = esr + rmsh[row32];
  const float mxr = fmaxf(xm, 0.2f * xm);  // exact masked row max

  f32x4 c0 = {}, c1 = {};
  float sum = 0.f;
  int cur = 0;

  for (int s = 0; s < KSTEPS; ++s) {
    uint4 nx;
    const bool hasnext = (s + 1 < KSTEPS);
    if (hasnext) nx = *(const uint4*)(wsrc + (s + 1) * 32);

    const int k0 = jh * 1024 + s * 32;
    const unsigned int mb = maskL[row32 * 260 + (k0 >> 3) + kg];
    const float4 ea = *(const float4*)&edsh[k0 + kg * 8];
    const float4 eb = *(const float4*)&edsh[k0 + kg * 8 + 4];
    const float ev[8] = {ea.x, ea.y, ea.z, ea.w, eb.x, eb.y, eb.z, eb.w};
    float p[8];
#pragma unroll
    for (int j = 0; j < 8; ++j) {
      const float x = esr + ev[j];
      const float y = fmaxf(x, 0.2f * x);
      float z = fminf(y - mxr, 0.f);  // belt-and-suspenders clamp
      z = (mb & (1u << j)) ? z : -1e30f;
      const float pj = __expf(z);
      p[j] = pj;
      sum += pj;
    }
    union { unsigned int u[4]; short8 v8; } af;
    af.u[0] = pk_bf16(p[0], p[1]);
    af.u[1] = pk_bf16(p[2], p[3]);
    af.u[2] = pk_bf16(p[4], p[5]);
    af.u[3] = pk_bf16(p[6], p[7]);

    const short8 b0 = *(const short8*)&whL[cur][jh][row16 * 40 + kg * 8];
    const short8 b1 = *(const short8*)&whL[cur][jh][(16 + row16) * 40 + kg * 8];
    c0 = __builtin_amdgcn_mfma_f32_16x16x32_bf16(af.v8, b0, c0, 0, 0, 0);
    c1 = __builtin_amdgcn_mfma_f32_16x16x32_bf16(af.v8, b1, c1, 0, 0, 0);

    __syncthreads();
    if (hasnext) {
      *(uint4*)&whL[cur ^ 1][jt][sr * 40 + sc * 8] = nx;
      __syncthreads();
    }
    cur ^= 1;
  }

  // ---- epilogue: combine j-halves, normalize, store ----
  sum += __shfl_xor(sum, 16, 64);
  sum += __shfl_xor(sum, 32, 64);
  if (lane < 16) sumsh[tile][jh][lane] = sum;
#pragma unroll
  for (int r = 0; r < 4; ++r) {
    redc[tile][jh][kg * 4 + r][row16] = c0[r];
    redc[tile][jh][kg * 4 + r][16 + row16] = c1[r];
  }
  __syncthreads();

  const int r32 = tid >> 3;
  const int c4 = (tid & 7) * 4;
  const int tl = r32 >> 4, rr = r32 & 15;
  const float inv = 1.f / fmaxf(sumsh[tl][0][rr] + sumsh[tl][1][rr], 1e-30f);
  float4 o;
  o.x = (redc[tl][0][rr][c4 + 0] + redc[tl][1][rr][c4 + 0]) * inv;
  o.y = (redc[tl][0][rr][c4 + 1] + redc[tl][1][rr][c4 + 1]) * inv;
  o.z = (redc[tl][0][rr][c4 + 2] + redc[tl][1][rr][c4 + 2]) * inv;
  o.w = (redc[tl][0][rr][c4 + 3] + redc[tl][1][rr][c4 + 3]) * inv;
  const int b = bh >> 2, hh = bh & 3;
  *(float4*)&out[((size_t)(b * N_ + i0 + r32)) * (H_ * D_) + hh * 32 + c4] = o;
}

// ---------------------------------------------------------------------------
extern "C" void kernel_launch(void* const* d_in, const int* in_sizes, int n_in,
                              void* d_out, int out_size, void* d_ws,
                              size_t ws_size, hipStream_t stream) {
  const float* h = (const float*)d_in[0];
  const int* adj = (const int*)d_in[1];
  const float* W = (const float*)d_in[2];
  const float* a = (const float*)d_in[3];
  char* ws = (char*)d_ws;
  u16* WhT = (u16*)ws;                                   // 2 MB
  float* es = (float*)(ws + (2u << 20));                 // 128 KB
  float* ed = (float*)(ws + (2u << 20) + (128u << 10));  // 128 KB
  unsigned long long* mask =
      (unsigned long long*)(ws + (2u << 20) + (256u << 10));   // 512 KB
  float* rowmaxed = (float*)(ws + (2u << 20) + (768u << 10));  // 128 KB
  float* out = (float*)d_out;

  wh_kernel<<<B_ * N_ / NPB, 256, 0, stream>>>(h, W, a, WhT, es, ed);
  pack_kernel<<<N_ * N_ / 256, 256, 0, stream>>>(adj, mask);
  rowmax_kernel<<<BH * (N_ / RMROWS), 256, 0, stream>>>(
      ed, (const unsigned int*)mask, rowmaxed);
  attn_kernel<<<BH * (N_ / ROWS), 256, 0, stream>>>(
      es, ed, rowmaxed, WhT, (const unsigned int*)mask, out);
}